// Round 17
// baseline (86.130 us; speedup 1.0000x reference)
//
#include <hip/hip_runtime.h>
#include <stdint.h>

typedef float f32x4 __attribute__((ext_vector_type(4)));
typedef long long i64;
typedef long long i64x2 __attribute__((ext_vector_type(2)));

// ArcFace constants (margin=0.5, scale=70)
constexpr float COS_M = 0.8775825618903728f;
constexpr float SIN_M = 0.4794255386042030f;
constexpr float MM    = 0.2397127693021015f;   // sin(pi-0.5)*0.5
constexpr float SCALE = 70.0f;
constexpr float LOG2E = 1.4426950408889634f;
constexpr float CA =  SCALE * COS_M * LOG2E;   // coeff on cos
constexpr float CB =  SCALE * SIN_M * LOG2E;   // coeff on sin
constexpr float CC = -SCALE * LOG2E;           // -70 shift, log2 domain

// skip threshold: c < 0.30 -> tt < -120.6 (log2); measured absmax 0.0625
// (threshold 0.2) across R5-R16, deterministic. Wave-uniform skip.
constexpr float C0 = 0.30f;

constexpr int NB = 2048, NC = 100000, ND = 128;
constexpr int NCP = 102400;                    // padded classes = 128 cg x 800
// k_main: grid = 8 rb x 128 cg = 1024 blocks = 4/CU, 16 waves/CU.
// Wave = 64 rows x 800 cols (m=4): B-frag feeds 16 MFMAs (R16: 8) ->
// B L2-traffic halves to (2048/64) x 13.1MB = 419MB (~12us), below the
// 26us MFMA floor. Zero LDS / zero barriers; B fragment-major, L2-resident.

// fragment-major dword index for dword d (0..31) of class-col c:
//   n=c>>4, r=c&15; p=d>>4, k1=(d>>3)&1, q=(d>>1)&3, w=d&1
//   idx32 = n*512 + p*256 + q*64 + r*4 + k1*2 + w
__device__ __forceinline__ uint32_t wfrag_idx(int c, int d) {
  const int n = c >> 4, r = c & 15;
  return (uint32_t)(n * 512 + (d >> 4) * 256 + ((d >> 1) & 3) * 64
                    + r * 4 + ((d >> 3) & 1) * 2 + (d & 1));
}

// ---- normalize x rows -> fp8 e4m3, linear 128B/row; zero rowsum ----
__global__ void __launch_bounds__(256) k_norm_x(const float* __restrict__ x,
                                                uint32_t* __restrict__ xn32,
                                                float* __restrict__ rowsum) {
  const int wv = threadIdx.x >> 6, lane = threadIdx.x & 63;
  if (blockIdx.x < 8) rowsum[blockIdx.x * 256 + threadIdx.x] = 0.0f;
  const int row = blockIdx.x * 4 + wv;                  // 512 blocks
  const float2 v = reinterpret_cast<const float2*>(x + row * ND)[lane];
  float ss = v.x * v.x + v.y * v.y;
  #pragma unroll
  for (int off = 1; off < 64; off <<= 1) ss += __shfl_xor(ss, off, 64);
  const float sc = __builtin_amdgcn_rsqf(fmaxf(ss, 1e-24f));
  if (lane < 32) {
    const float4 f = reinterpret_cast<const float4*>(x + row * ND)[lane];
    int pk = __builtin_amdgcn_cvt_pk_fp8_f32(f.x * sc, f.y * sc, 0, false);
    pk = __builtin_amdgcn_cvt_pk_fp8_f32(f.z * sc, f.w * sc, pk, true);
    xn32[row * 32 + lane] = (uint32_t)pk;
  }
}

// ---- normalize w rows -> fp8 e4m3 in fragment-major layout ----
// rows NC..NCP-1 zero-filled (cos=0 -> wave-uniform skip in k_main)
__global__ void __launch_bounds__(256) k_norm_w(const float* __restrict__ w,
                                                uint32_t* __restrict__ wn32) {
  const int wv = threadIdx.x >> 6, lane = threadIdx.x & 63;
  const int c = blockIdx.x * 4 + wv;                    // 25600 blocks
  if (c >= NC) {
    if (lane < 32) wn32[wfrag_idx(c, lane)] = 0u;
    return;
  }
  const float2 v = reinterpret_cast<const float2*>(w + c * ND)[lane];
  float ss = v.x * v.x + v.y * v.y;
  #pragma unroll
  for (int off = 1; off < 64; off <<= 1) ss += __shfl_xor(ss, off, 64);
  const float sc = __builtin_amdgcn_rsqf(fmaxf(ss, 1e-24f));
  if (lane < 32) {
    const float4 f = reinterpret_cast<const float4*>(w + c * ND)[lane];
    int pk = __builtin_amdgcn_cvt_pk_fp8_f32(f.x * sc, f.y * sc, 0, false);
    pk = __builtin_amdgcn_cvt_pk_fp8_f32(f.z * sc, f.w * sc, pk, true);
    wn32[wfrag_idx(c, lane)] = (uint32_t)pk;
  }
}

// ---- target-column cosines: exact f32 (for logit_t) + fp8-replica (for swap) ----
__global__ void __launch_bounds__(256) k_tdot(const float* __restrict__ x,
                                              const float* __restrict__ w,
                                              const uint32_t* __restrict__ xn32,
                                              const uint32_t* __restrict__ wn32,
                                              const int* __restrict__ tgt,
                                              float2* __restrict__ cost) {
  const int wv = threadIdx.x >> 6, lane = threadIdx.x & 63;
  const int b = blockIdx.x * 4 + wv;                    // 512 blocks
  const int t = tgt[b];
  const float2 xv = reinterpret_cast<const float2*>(x + b * ND)[lane];
  const float2 wv2 = reinterpret_cast<const float2*>(w + t * ND)[lane];
  float dot = xv.x * wv2.x + xv.y * wv2.y;
  float ssx = xv.x * xv.x + xv.y * xv.y;
  float ssw = wv2.x * wv2.x + wv2.y * wv2.y;
  float dq = 0.0f;
  if (lane < 32) {
    const uint32_t xa = xn32[b * 32 + lane];
    const uint32_t wa = wn32[wfrag_idx(t, lane)];
    dq += __builtin_amdgcn_cvt_f32_fp8(xa, 0) * __builtin_amdgcn_cvt_f32_fp8(wa, 0);
    dq += __builtin_amdgcn_cvt_f32_fp8(xa, 1) * __builtin_amdgcn_cvt_f32_fp8(wa, 1);
    dq += __builtin_amdgcn_cvt_f32_fp8(xa, 2) * __builtin_amdgcn_cvt_f32_fp8(wa, 2);
    dq += __builtin_amdgcn_cvt_f32_fp8(xa, 3) * __builtin_amdgcn_cvt_f32_fp8(wa, 3);
  }
  #pragma unroll
  for (int off = 1; off < 64; off <<= 1) {
    dot += __shfl_xor(dot, off, 64);
    ssx += __shfl_xor(ssx, off, 64);
    ssw += __shfl_xor(ssw, off, 64);
    dq  += __shfl_xor(dq,  off, 64);
  }
  if (lane == 0) {
    const float de = dot / (sqrtf(ssx) * sqrtf(ssw));
    cost[b] = make_float2(de, dq);
  }
}

// ---- main fused GEMM (fp8, global->VGPR B, zero barriers/LDS, m=4) ----
__global__ void __launch_bounds__(256, 4) k_main(const uint8_t* __restrict__ xn8,
                                                 const uint32_t* __restrict__ wn32,
                                                 float* __restrict__ rowsum) {
  const int wv = threadIdx.x >> 6, lane = threadIdx.x & 63;
  const int q = lane >> 4, r = lane & 15;
  // XCD-affine: xcd = b&7 owns cgs [16*xcd, 16*xcd+16)  (1.6MB/XCD L2-resident)
  const int xcd = blockIdx.x & 7, idx = blockIdx.x >> 3;  // idx 0..127
  const int cg = xcd * 16 + (idx >> 3);                 // 0..127
  const int rb = idx & 7;                               // 0..7
  const int rowbase = rb * 256 + wv * 64;
  const int fragbase = cg * 50;                         // 50 16-col frags per cg

  // A fragments: 64 rows x K=128; lane(16q+r) holds k=[32kk+8q,+8) of row
  i64 afrag[4][4];
  #pragma unroll
  for (int m = 0; m < 4; ++m)
    #pragma unroll
    for (int kk = 0; kk < 4; ++kk)
      afrag[m][kk] = *reinterpret_cast<const i64*>(
          xn8 + (size_t)(rowbase + 16 * m + r) * 128 + 32 * kk + 8 * q);

  float rsum[4][4] = {{0.f,0.f,0.f,0.f},{0.f,0.f,0.f,0.f},
                      {0.f,0.f,0.f,0.f},{0.f,0.f,0.f,0.f}};

  auto loadB = [&](i64* buf, int nn) {
    const uint32_t* base = wn32 + (size_t)(fragbase + nn) * 512 + lane * 4;
    const i64x2 lo = *reinterpret_cast<const i64x2*>(base);          // kk=0,1
    const i64x2 hi = *reinterpret_cast<const i64x2*>(base + 256);    // kk=2,3
    buf[0] = lo[0]; buf[1] = lo[1]; buf[2] = hi[0]; buf[3] = hi[1];
  };
  auto compute = [&](const i64* buf) {
    f32x4 acc[4] = {};
    __builtin_amdgcn_s_setprio(1);
    #pragma unroll
    for (int kk = 0; kk < 4; ++kk)
      #pragma unroll
      for (int m = 0; m < 4; ++m)
        acc[m] = __builtin_amdgcn_mfma_f32_16x16x32_fp8_fp8(
            afrag[m][kk], buf[kk], acc[m], 0, 0, 0);
    __builtin_amdgcn_s_setprio(0);
    #pragma unroll
    for (int m = 0; m < 4; ++m)
      #pragma unroll
      for (int e = 0; e < 4; ++e) {
        const float c = acc[m][e];
        if (__any(c > C0)) {
          const float s2 = fmaxf(fmaf(-c, c, 1.0f), 0.0f);
          const float sn = __builtin_amdgcn_sqrtf(s2);
          float tt = fmaf(c, CA, CC);
          tt = fmaf(sn, -CB, tt);
          rsum[m][e] += __builtin_amdgcn_exp2f(tt);
        }
      }
  };

  i64 bA[4], bB[4];
  loadB(bA, 0);
  for (int nn = 0; nn < 50; nn += 2) {
    loadB(bB, nn + 1);                  // prefetch odd frag
    compute(bA);                        // compute even frag
    if (nn + 2 < 50) loadB(bA, nn + 2);
    compute(bB);
  }

  // reduce over the 16 class-lanes, then one atomic per row
  #pragma unroll
  for (int m = 0; m < 4; ++m)
    #pragma unroll
    for (int e = 0; e < 4; ++e) {
      float v = rsum[m][e];
      #pragma unroll
      for (int off = 1; off < 16; off <<= 1) v += __shfl_xor(v, off, 64);
      if (r == 0)
        atomicAdd(&rowsum[rowbase + 16 * m + 4 * q + e], v);
    }
}

// ---- finalize: target-term swap, log, mean ----
__global__ void __launch_bounds__(256) k_final(const float* __restrict__ rowsum,
                                               const float2* __restrict__ cost,
                                               float* __restrict__ out) {
  __shared__ float red[256];
  float part = 0.f;
  for (int b = threadIdx.x; b < NB; b += 256) {
    const float2 cb = cost[b];
    const float ce = fminf(cb.x, 1.0f);                       // exact cos (clip)
    const float cq = cb.y;                                    // fp8-replica cos
    const float s2 = fmaxf(fmaf(-cq, cq, 1.0f), 0.0f);
    const float sn = __builtin_amdgcn_sqrtf(s2);
    float tt = fmaf(cq, CA, CC);
    tt = fmaf(sn, -CB, tt);
    const float v_ctm = (cq > C0) ? __builtin_amdgcn_exp2f(tt) : 0.0f;  // k_main's add for target col
    const float logit_t = SCALE * (ce - MM);                  // true target logit
    const float v_tgt = __builtin_amdgcn_exp2f((logit_t - SCALE) * LOG2E);
    float sum = rowsum[b] - v_ctm + v_tgt;
    sum = fmaxf(sum, 1e-37f);
    part += __builtin_amdgcn_logf(sum) * 0.6931471805599453f + SCALE - logit_t;
  }
  red[threadIdx.x] = part;
  __syncthreads();
  #pragma unroll
  for (int s = 128; s > 0; s >>= 1) {
    if (threadIdx.x < s) red[threadIdx.x] += red[threadIdx.x + s];
    __syncthreads();
  }
  if (threadIdx.x == 0) out[0] = red[0] * (1.0f / NB);
}

extern "C" void kernel_launch(void* const* d_in, const int* in_sizes, int n_in,
                              void* d_out, int out_size, void* d_ws, size_t ws_size,
                              hipStream_t stream) {
  const float* x   = (const float*)d_in[0];
  const int*   tgt = (const int*)d_in[1];
  const float* w   = (const float*)d_in[2];
  float* out = (float*)d_out;

  char* ws = (char*)d_ws;
  const size_t WN_B = (size_t)NCP * 128;       // 13,107,200
  const size_t XN_B = (size_t)NB * 128;        // 262,144
  uint32_t* wn32   = (uint32_t*)ws;
  uint32_t* xn32   = (uint32_t*)(ws + WN_B);
  float2*   cost   = (float2*)(ws + WN_B + XN_B);
  float*    rowsum = (float*)(ws + WN_B + XN_B + NB * 8);
  if (ws_size < WN_B + XN_B + (size_t)NB * 12) return;

  k_norm_x<<<512,   256, 0, stream>>>(x, xn32, rowsum);
  k_norm_w<<<25600, 256, 0, stream>>>(w, wn32);
  k_tdot <<<512,   256, 0, stream>>>(x, w, xn32, wn32, tgt, cost);
  k_main <<<1024,  256, 0, stream>>>((const uint8_t*)xn32, wn32, rowsum);
  k_final<<<1,     256, 0, stream>>>(rowsum, cost, out);
}

// Round 18
// 74.327 us; speedup vs baseline: 1.1588x; 1.1588x over previous
//
#include <hip/hip_runtime.h>
#include <stdint.h>

typedef float f32x4 __attribute__((ext_vector_type(4)));
typedef int   i32x4 __attribute__((ext_vector_type(4)));
typedef int   i32x8 __attribute__((ext_vector_type(8)));

// ArcFace constants (margin=0.5, scale=70)
constexpr float COS_M = 0.8775825618903728f;
constexpr float SIN_M = 0.4794255386042030f;
constexpr float MM    = 0.2397127693021015f;   // sin(pi-0.5)*0.5
constexpr float SCALE = 70.0f;
constexpr float LOG2E = 1.4426950408889634f;
constexpr float CA =  SCALE * COS_M * LOG2E;   // coeff on cos
constexpr float CB =  SCALE * SIN_M * LOG2E;   // coeff on sin
constexpr float CC = -SCALE * LOG2E;           // -70 shift, log2 domain

// skip threshold: c < 0.30 -> tt < -120.6 (log2); measured absmax 0.0625
// (threshold 0.2) across R5-R17, deterministic. Wave-uniform skip.
constexpr float C0 = 0.30f;
constexpr int SCL1 = 0x7f7f7f7f;               // E8M0 127 = 1.0 per 32-block

constexpr int NB = 2048, NC = 100000, ND = 128;
constexpr int NCP = 102400;                    // padded classes = 128 cg x 800
// k_main: R16 skeleton (2048 blocks = 16 rb x 128 cg, 8 waves/SIMD, zero
// LDS/barriers, B fragment-major L2-resident) with the 4 chained K=32 fp8
// MFMAs replaced by ONE mfma_scale_f32_16x16x128_f8f6f4 (scale=1.0):
// MFMA issue/SIMD 62k -> 27.6k cyc (floor 26 -> 11.5us at 4661 TF).

// scaled-K128 fragment-major dword index for dword d (0..31) of col c:
// lane l of frag n reads col 16n+(l&15), k=(l>>4)*32..+32 -> 8 consecutive
// dwords at n*512 + (l>>4)*128 + (l&15)*8.
__device__ __forceinline__ uint32_t widx(int c, int d) {
  return (uint32_t)((c >> 4) * 512 + (d >> 3) * 128 + (c & 15) * 8 + (d & 7));
}

// ---- normalize x rows -> fp8 e4m3, linear 128B/row; zero rowsum ----
__global__ void __launch_bounds__(256) k_norm_x(const float* __restrict__ x,
                                                uint32_t* __restrict__ xn32,
                                                float* __restrict__ rowsum) {
  const int wv = threadIdx.x >> 6, lane = threadIdx.x & 63;
  if (blockIdx.x < 8) rowsum[blockIdx.x * 256 + threadIdx.x] = 0.0f;
  const int row = blockIdx.x * 4 + wv;                  // 512 blocks
  const float2 v = reinterpret_cast<const float2*>(x + row * ND)[lane];
  float ss = v.x * v.x + v.y * v.y;
  #pragma unroll
  for (int off = 1; off < 64; off <<= 1) ss += __shfl_xor(ss, off, 64);
  const float sc = __builtin_amdgcn_rsqf(fmaxf(ss, 1e-24f));
  if (lane < 32) {
    const float4 f = reinterpret_cast<const float4*>(x + row * ND)[lane];
    int pk = __builtin_amdgcn_cvt_pk_fp8_f32(f.x * sc, f.y * sc, 0, false);
    pk = __builtin_amdgcn_cvt_pk_fp8_f32(f.z * sc, f.w * sc, pk, true);
    xn32[row * 32 + lane] = (uint32_t)pk;
  }
}

// ---- normalize w rows -> fp8 e4m3 in scaled-K128 fragment-major layout ----
// rows NC..NCP-1 zero-filled (cos=0 -> wave-uniform skip in k_main)
__global__ void __launch_bounds__(256) k_norm_w(const float* __restrict__ w,
                                                uint32_t* __restrict__ wn32) {
  const int wv = threadIdx.x >> 6, lane = threadIdx.x & 63;
  const int c = blockIdx.x * 4 + wv;                    // 25600 blocks
  if (c >= NC) {
    if (lane < 32) wn32[widx(c, lane)] = 0u;
    return;
  }
  const float2 v = reinterpret_cast<const float2*>(w + c * ND)[lane];
  float ss = v.x * v.x + v.y * v.y;
  #pragma unroll
  for (int off = 1; off < 64; off <<= 1) ss += __shfl_xor(ss, off, 64);
  const float sc = __builtin_amdgcn_rsqf(fmaxf(ss, 1e-24f));
  if (lane < 32) {
    const float4 f = reinterpret_cast<const float4*>(w + c * ND)[lane];
    int pk = __builtin_amdgcn_cvt_pk_fp8_f32(f.x * sc, f.y * sc, 0, false);
    pk = __builtin_amdgcn_cvt_pk_fp8_f32(f.z * sc, f.w * sc, pk, true);
    wn32[widx(c, lane)] = (uint32_t)pk;
  }
}

// ---- target-column cosines: exact f32 (for logit_t) + fp8-replica (for swap) ----
__global__ void __launch_bounds__(256) k_tdot(const float* __restrict__ x,
                                              const float* __restrict__ w,
                                              const uint32_t* __restrict__ xn32,
                                              const uint32_t* __restrict__ wn32,
                                              const int* __restrict__ tgt,
                                              float2* __restrict__ cost) {
  const int wv = threadIdx.x >> 6, lane = threadIdx.x & 63;
  const int b = blockIdx.x * 4 + wv;                    // 512 blocks
  const int t = tgt[b];
  const float2 xv = reinterpret_cast<const float2*>(x + b * ND)[lane];
  const float2 wv2 = reinterpret_cast<const float2*>(w + t * ND)[lane];
  float dot = xv.x * wv2.x + xv.y * wv2.y;
  float ssx = xv.x * xv.x + xv.y * xv.y;
  float ssw = wv2.x * wv2.x + wv2.y * wv2.y;
  float dq = 0.0f;
  if (lane < 32) {
    const uint32_t xa = xn32[b * 32 + lane];
    const uint32_t wa = wn32[widx(t, lane)];
    dq += __builtin_amdgcn_cvt_f32_fp8(xa, 0) * __builtin_amdgcn_cvt_f32_fp8(wa, 0);
    dq += __builtin_amdgcn_cvt_f32_fp8(xa, 1) * __builtin_amdgcn_cvt_f32_fp8(wa, 1);
    dq += __builtin_amdgcn_cvt_f32_fp8(xa, 2) * __builtin_amdgcn_cvt_f32_fp8(wa, 2);
    dq += __builtin_amdgcn_cvt_f32_fp8(xa, 3) * __builtin_amdgcn_cvt_f32_fp8(wa, 3);
  }
  #pragma unroll
  for (int off = 1; off < 64; off <<= 1) {
    dot += __shfl_xor(dot, off, 64);
    ssx += __shfl_xor(ssx, off, 64);
    ssw += __shfl_xor(ssw, off, 64);
    dq  += __shfl_xor(dq,  off, 64);
  }
  if (lane == 0) {
    const float de = dot / (sqrtf(ssx) * sqrtf(ssw));
    cost[b] = make_float2(de, dq);
  }
}

// ---- main fused GEMM (MX-scaled fp8 K=128, global->VGPR B, no LDS/barriers) ----
__global__ void __launch_bounds__(256, 4) k_main(const uint32_t* __restrict__ xn32,
                                                 const uint32_t* __restrict__ wn32,
                                                 float* __restrict__ rowsum) {
  const int wv = threadIdx.x >> 6, lane = threadIdx.x & 63;
  const int q = lane >> 4, r = lane & 15;
  // XCD-affine: xcd = b&7 owns cgs [16*xcd, 16*xcd+16)  (1.6MB/XCD L2-resident)
  const int xcd = blockIdx.x & 7, idx = blockIdx.x >> 3;  // idx 0..255
  const int cg = xcd * 16 + (idx >> 4);                 // 0..127
  const int rb = idx & 15;                              // 0..15
  const int rowbase = rb * 128 + wv * 32;
  const int fragbase = cg * 50;                         // 50 16-col frags per cg

  // A fragments: m=2 x (16 rows); lane holds row=rowbase+16m+r, k=q*32..+32
  i32x8 afrag[2];
  #pragma unroll
  for (int m = 0; m < 2; ++m) {
    const uint32_t* ap = xn32 + (size_t)(rowbase + 16 * m + r) * 32 + q * 8;
    const i32x4 lo = *reinterpret_cast<const i32x4*>(ap);
    const i32x4 hi = *reinterpret_cast<const i32x4*>(ap + 4);
    afrag[m][0] = lo[0]; afrag[m][1] = lo[1]; afrag[m][2] = lo[2]; afrag[m][3] = lo[3];
    afrag[m][4] = hi[0]; afrag[m][5] = hi[1]; afrag[m][6] = hi[2]; afrag[m][7] = hi[3];
  }

  float rsum[2][4] = {{0.f,0.f,0.f,0.f},{0.f,0.f,0.f,0.f}};

  auto loadB = [&](i32x8* buf, int nn) {
    const uint32_t* base = wn32 + (size_t)(fragbase + nn) * 512 + q * 128 + r * 8;
    const i32x4 lo = *reinterpret_cast<const i32x4*>(base);
    const i32x4 hi = *reinterpret_cast<const i32x4*>(base + 4);
    (*buf)[0] = lo[0]; (*buf)[1] = lo[1]; (*buf)[2] = lo[2]; (*buf)[3] = lo[3];
    (*buf)[4] = hi[0]; (*buf)[5] = hi[1]; (*buf)[6] = hi[2]; (*buf)[7] = hi[3];
  };
  auto compute = [&](const i32x8& buf) {
    f32x4 acc[2] = {};
    __builtin_amdgcn_s_setprio(1);
    #pragma unroll
    for (int m = 0; m < 2; ++m)
      acc[m] = __builtin_amdgcn_mfma_scale_f32_16x16x128_f8f6f4(
          afrag[m], buf, acc[m], 0 /*A=fp8*/, 0 /*B=fp8*/,
          0, SCL1, 0, SCL1);
    __builtin_amdgcn_s_setprio(0);
    #pragma unroll
    for (int m = 0; m < 2; ++m) {
      const float mx = fmaxf(fmaxf(acc[m][0], acc[m][1]),
                             fmaxf(acc[m][2], acc[m][3]));
      if (__any(mx > C0)) {
        #pragma unroll
        for (int e = 0; e < 4; ++e) {
          const float c = acc[m][e];
          const float s2 = fmaxf(fmaf(-c, c, 1.0f), 0.0f);
          const float sn = __builtin_amdgcn_sqrtf(s2);
          float tt = fmaf(c, CA, CC);
          tt = fmaf(sn, -CB, tt);
          rsum[m][e] += __builtin_amdgcn_exp2f(tt);
        }
      }
    }
  };

  i32x8 bA, bB;
  loadB(&bA, 0);
  for (int nn = 0; nn < 50; nn += 2) {
    loadB(&bB, nn + 1);                 // prefetch odd frag
    compute(bA);                        // compute even frag
    if (nn + 2 < 50) loadB(&bA, nn + 2);
    compute(bB);
  }

  // reduce over the 16 class-lanes, then one atomic per row
  #pragma unroll
  for (int m = 0; m < 2; ++m)
    #pragma unroll
    for (int e = 0; e < 4; ++e) {
      float v = rsum[m][e];
      #pragma unroll
      for (int off = 1; off < 16; off <<= 1) v += __shfl_xor(v, off, 64);
      if (r == 0)
        atomicAdd(&rowsum[rowbase + 16 * m + 4 * q + e], v);
    }
}

// ---- finalize: target-term swap, log, mean ----
__global__ void __launch_bounds__(256) k_final(const float* __restrict__ rowsum,
                                               const float2* __restrict__ cost,
                                               float* __restrict__ out) {
  __shared__ float red[256];
  float part = 0.f;
  for (int b = threadIdx.x; b < NB; b += 256) {
    const float2 cb = cost[b];
    const float ce = fminf(cb.x, 1.0f);                       // exact cos (clip)
    const float cq = cb.y;                                    // fp8-replica cos
    const float s2 = fmaxf(fmaf(-cq, cq, 1.0f), 0.0f);
    const float sn = __builtin_amdgcn_sqrtf(s2);
    float tt = fmaf(cq, CA, CC);
    tt = fmaf(sn, -CB, tt);
    // k_main's add for the target column: fires if its m-group max > C0;
    // group-max >= cq, and when cq <= C0 the term underflows to 0 anyway,
    // so replicating with (cq > C0) matches to f32 precision.
    const float v_ctm = (cq > C0) ? __builtin_amdgcn_exp2f(tt) : 0.0f;
    const float logit_t = SCALE * (ce - MM);                  // true target logit
    const float v_tgt = __builtin_amdgcn_exp2f((logit_t - SCALE) * LOG2E);
    float sum = rowsum[b] - v_ctm + v_tgt;
    sum = fmaxf(sum, 1e-37f);
    part += __builtin_amdgcn_logf(sum) * 0.6931471805599453f + SCALE - logit_t;
  }
  red[threadIdx.x] = part;
  __syncthreads();
  #pragma unroll
  for (int s = 128; s > 0; s >>= 1) {
    if (threadIdx.x < s) red[threadIdx.x] += red[threadIdx.x + s];
    __syncthreads();
  }
  if (threadIdx.x == 0) out[0] = red[0] * (1.0f / NB);
}

extern "C" void kernel_launch(void* const* d_in, const int* in_sizes, int n_in,
                              void* d_out, int out_size, void* d_ws, size_t ws_size,
                              hipStream_t stream) {
  const float* x   = (const float*)d_in[0];
  const int*   tgt = (const int*)d_in[1];
  const float* w   = (const float*)d_in[2];
  float* out = (float*)d_out;

  char* ws = (char*)d_ws;
  const size_t WN_B = (size_t)NCP * 128;       // 13,107,200
  const size_t XN_B = (size_t)NB * 128;        // 262,144
  uint32_t* wn32   = (uint32_t*)ws;
  uint32_t* xn32   = (uint32_t*)(ws + WN_B);
  float2*   cost   = (float2*)(ws + WN_B + XN_B);
  float*    rowsum = (float*)(ws + WN_B + XN_B + NB * 8);
  if (ws_size < WN_B + XN_B + (size_t)NB * 12) return;

  k_norm_x<<<512,   256, 0, stream>>>(x, xn32, rowsum);
  k_norm_w<<<25600, 256, 0, stream>>>(w, wn32);
  k_tdot <<<512,   256, 0, stream>>>(x, w, xn32, wn32, tgt, cost);
  k_main <<<2048,  256, 0, stream>>>(xn32, wn32, rowsum);
  k_final<<<1,     256, 0, stream>>>(rowsum, cost, out);
}

// Round 19
// 70.432 us; speedup vs baseline: 1.2229x; 1.0553x over previous
//
#include <hip/hip_runtime.h>
#include <stdint.h>

typedef float f32x4 __attribute__((ext_vector_type(4)));
typedef int   i32x4 __attribute__((ext_vector_type(4)));
typedef int   i32x8 __attribute__((ext_vector_type(8)));

// ArcFace constants (margin=0.5, scale=70)
constexpr float COS_M = 0.8775825618903728f;
constexpr float SIN_M = 0.4794255386042030f;
constexpr float MM    = 0.2397127693021015f;   // sin(pi-0.5)*0.5
constexpr float SCALE = 70.0f;
constexpr float LOG2E = 1.4426950408889634f;
constexpr float CA =  SCALE * COS_M * LOG2E;   // coeff on cos
constexpr float CB =  SCALE * SIN_M * LOG2E;   // coeff on sin
constexpr float CC = -SCALE * LOG2E;           // -70 shift, log2 domain

// skip threshold: c < 0.30 -> tt < -120.6 (log2); measured absmax 0.0625
// (threshold 0.2) across R5-R18, deterministic. Wave-uniform skip.
constexpr float C0 = 0.30f;
constexpr int SCL1 = 0x7f7f7f7f;               // E8M0 127 = 1.0 per 32-block

constexpr int NB = 2048, NC = 100000, ND = 128;
constexpr int NCP = 102400;                    // padded classes = 128 cg x 800
// k_main: R18 structure (2048 blocks = 16 rb x 128 cg, 8 waves/SIMD, zero
// LDS/barriers, B fragment-major L2-resident, mfma_scale K=128) with the
// B-prefetch pipeline deepened 1 -> 3 frags ahead (4 named buffers):
// ~330 cyc of independent work in flight vs ~200-300 cyc L2 latency.

// scaled-K128 fragment-major dword index for dword d (0..31) of col c:
// lane l of frag n reads col 16n+(l&15), k=(l>>4)*32..+32 -> 8 consecutive
// dwords at n*512 + (l>>4)*128 + (l&15)*8.
__device__ __forceinline__ uint32_t widx(int c, int d) {
  return (uint32_t)((c >> 4) * 512 + (d >> 3) * 128 + (c & 15) * 8 + (d & 7));
}

// ---- normalize x rows -> fp8 e4m3, linear 128B/row; zero rowsum ----
__global__ void __launch_bounds__(256) k_norm_x(const float* __restrict__ x,
                                                uint32_t* __restrict__ xn32,
                                                float* __restrict__ rowsum) {
  const int wv = threadIdx.x >> 6, lane = threadIdx.x & 63;
  if (blockIdx.x < 8) rowsum[blockIdx.x * 256 + threadIdx.x] = 0.0f;
  const int row = blockIdx.x * 4 + wv;                  // 512 blocks
  const float2 v = reinterpret_cast<const float2*>(x + row * ND)[lane];
  float ss = v.x * v.x + v.y * v.y;
  #pragma unroll
  for (int off = 1; off < 64; off <<= 1) ss += __shfl_xor(ss, off, 64);
  const float sc = __builtin_amdgcn_rsqf(fmaxf(ss, 1e-24f));
  if (lane < 32) {
    const float4 f = reinterpret_cast<const float4*>(x + row * ND)[lane];
    int pk = __builtin_amdgcn_cvt_pk_fp8_f32(f.x * sc, f.y * sc, 0, false);
    pk = __builtin_amdgcn_cvt_pk_fp8_f32(f.z * sc, f.w * sc, pk, true);
    xn32[row * 32 + lane] = (uint32_t)pk;
  }
}

// ---- normalize w rows -> fp8 e4m3 in scaled-K128 fragment-major layout ----
// rows NC..NCP-1 zero-filled (cos=0 -> wave-uniform skip in k_main)
__global__ void __launch_bounds__(256) k_norm_w(const float* __restrict__ w,
                                                uint32_t* __restrict__ wn32) {
  const int wv = threadIdx.x >> 6, lane = threadIdx.x & 63;
  const int c = blockIdx.x * 4 + wv;                    // 25600 blocks
  if (c >= NC) {
    if (lane < 32) wn32[widx(c, lane)] = 0u;
    return;
  }
  const float2 v = reinterpret_cast<const float2*>(w + c * ND)[lane];
  float ss = v.x * v.x + v.y * v.y;
  #pragma unroll
  for (int off = 1; off < 64; off <<= 1) ss += __shfl_xor(ss, off, 64);
  const float sc = __builtin_amdgcn_rsqf(fmaxf(ss, 1e-24f));
  if (lane < 32) {
    const float4 f = reinterpret_cast<const float4*>(w + c * ND)[lane];
    int pk = __builtin_amdgcn_cvt_pk_fp8_f32(f.x * sc, f.y * sc, 0, false);
    pk = __builtin_amdgcn_cvt_pk_fp8_f32(f.z * sc, f.w * sc, pk, true);
    wn32[widx(c, lane)] = (uint32_t)pk;
  }
}

// ---- target-column cosines: exact f32 (for logit_t) + fp8-replica (for swap) ----
__global__ void __launch_bounds__(256) k_tdot(const float* __restrict__ x,
                                              const float* __restrict__ w,
                                              const uint32_t* __restrict__ xn32,
                                              const uint32_t* __restrict__ wn32,
                                              const int* __restrict__ tgt,
                                              float2* __restrict__ cost) {
  const int wv = threadIdx.x >> 6, lane = threadIdx.x & 63;
  const int b = blockIdx.x * 4 + wv;                    // 512 blocks
  const int t = tgt[b];
  const float2 xv = reinterpret_cast<const float2*>(x + b * ND)[lane];
  const float2 wv2 = reinterpret_cast<const float2*>(w + t * ND)[lane];
  float dot = xv.x * wv2.x + xv.y * wv2.y;
  float ssx = xv.x * xv.x + xv.y * xv.y;
  float ssw = wv2.x * wv2.x + wv2.y * wv2.y;
  float dq = 0.0f;
  if (lane < 32) {
    const uint32_t xa = xn32[b * 32 + lane];
    const uint32_t wa = wn32[widx(t, lane)];
    dq += __builtin_amdgcn_cvt_f32_fp8(xa, 0) * __builtin_amdgcn_cvt_f32_fp8(wa, 0);
    dq += __builtin_amdgcn_cvt_f32_fp8(xa, 1) * __builtin_amdgcn_cvt_f32_fp8(wa, 1);
    dq += __builtin_amdgcn_cvt_f32_fp8(xa, 2) * __builtin_amdgcn_cvt_f32_fp8(wa, 2);
    dq += __builtin_amdgcn_cvt_f32_fp8(xa, 3) * __builtin_amdgcn_cvt_f32_fp8(wa, 3);
  }
  #pragma unroll
  for (int off = 1; off < 64; off <<= 1) {
    dot += __shfl_xor(dot, off, 64);
    ssx += __shfl_xor(ssx, off, 64);
    ssw += __shfl_xor(ssw, off, 64);
    dq  += __shfl_xor(dq,  off, 64);
  }
  if (lane == 0) {
    const float de = dot / (sqrtf(ssx) * sqrtf(ssw));
    cost[b] = make_float2(de, dq);
  }
}

// ---- main fused GEMM (MX-scaled fp8 K=128, global->VGPR B, no LDS/barriers) ----
__global__ void __launch_bounds__(256, 4) k_main(const uint32_t* __restrict__ xn32,
                                                 const uint32_t* __restrict__ wn32,
                                                 float* __restrict__ rowsum) {
  const int wv = threadIdx.x >> 6, lane = threadIdx.x & 63;
  const int q = lane >> 4, r = lane & 15;
  // XCD-affine: xcd = b&7 owns cgs [16*xcd, 16*xcd+16)  (1.6MB/XCD L2-resident)
  const int xcd = blockIdx.x & 7, idx = blockIdx.x >> 3;  // idx 0..255
  const int cg = xcd * 16 + (idx >> 4);                 // 0..127
  const int rb = idx & 15;                              // 0..15
  const int rowbase = rb * 128 + wv * 32;
  const int fragbase = cg * 50;                         // 50 16-col frags per cg

  // A fragments: m=2 x (16 rows); lane holds row=rowbase+16m+r, k=q*32..+32
  i32x8 afrag[2];
  #pragma unroll
  for (int m = 0; m < 2; ++m) {
    const uint32_t* ap = xn32 + (size_t)(rowbase + 16 * m + r) * 32 + q * 8;
    const i32x4 lo = *reinterpret_cast<const i32x4*>(ap);
    const i32x4 hi = *reinterpret_cast<const i32x4*>(ap + 4);
    afrag[m][0] = lo[0]; afrag[m][1] = lo[1]; afrag[m][2] = lo[2]; afrag[m][3] = lo[3];
    afrag[m][4] = hi[0]; afrag[m][5] = hi[1]; afrag[m][6] = hi[2]; afrag[m][7] = hi[3];
  }

  float rsum[2][4] = {{0.f,0.f,0.f,0.f},{0.f,0.f,0.f,0.f}};

  auto loadB = [&](i32x8* buf, int nn) {
    const uint32_t* base = wn32 + (size_t)(fragbase + nn) * 512 + q * 128 + r * 8;
    const i32x4 lo = *reinterpret_cast<const i32x4*>(base);
    const i32x4 hi = *reinterpret_cast<const i32x4*>(base + 4);
    (*buf)[0] = lo[0]; (*buf)[1] = lo[1]; (*buf)[2] = lo[2]; (*buf)[3] = lo[3];
    (*buf)[4] = hi[0]; (*buf)[5] = hi[1]; (*buf)[6] = hi[2]; (*buf)[7] = hi[3];
  };
  auto compute = [&](const i32x8& buf) {
    f32x4 acc[2] = {};
    __builtin_amdgcn_s_setprio(1);
    #pragma unroll
    for (int m = 0; m < 2; ++m)
      acc[m] = __builtin_amdgcn_mfma_scale_f32_16x16x128_f8f6f4(
          afrag[m], buf, acc[m], 0 /*A=fp8*/, 0 /*B=fp8*/,
          0, SCL1, 0, SCL1);
    __builtin_amdgcn_s_setprio(0);
    #pragma unroll
    for (int m = 0; m < 2; ++m) {
      const float mx = fmaxf(fmaxf(acc[m][0], acc[m][1]),
                             fmaxf(acc[m][2], acc[m][3]));
      if (__any(mx > C0)) {
        #pragma unroll
        for (int e = 0; e < 4; ++e) {
          const float c = acc[m][e];
          const float s2 = fmaxf(fmaf(-c, c, 1.0f), 0.0f);
          const float sn = __builtin_amdgcn_sqrtf(s2);
          float tt = fmaf(c, CA, CC);
          tt = fmaf(sn, -CB, tt);
          rsum[m][e] += __builtin_amdgcn_exp2f(tt);
        }
      }
    }
  };

  // depth-3 prefetch pipeline, 4 named buffers (no runtime indexing)
  i32x8 b0, b1, b2, b3;
  loadB(&b0, 0);
  loadB(&b1, 1);
  loadB(&b2, 2);
  for (int nn = 0; nn < 48; nn += 4) {
    loadB(&b3, nn + 3);                   compute(b0);
    if (nn + 4 < 50) loadB(&b0, nn + 4);  compute(b1);
    if (nn + 5 < 50) loadB(&b1, nn + 5);  compute(b2);
    if (nn + 6 < 50) loadB(&b2, nn + 6);  compute(b3);
  }
  compute(b0);                            // frag 48
  compute(b1);                            // frag 49

  // reduce over the 16 class-lanes, then one atomic per row
  #pragma unroll
  for (int m = 0; m < 2; ++m)
    #pragma unroll
    for (int e = 0; e < 4; ++e) {
      float v = rsum[m][e];
      #pragma unroll
      for (int off = 1; off < 16; off <<= 1) v += __shfl_xor(v, off, 64);
      if (r == 0)
        atomicAdd(&rowsum[rowbase + 16 * m + 4 * q + e], v);
    }
}

// ---- finalize: target-term swap, log, mean ----
__global__ void __launch_bounds__(256) k_final(const float* __restrict__ rowsum,
                                               const float2* __restrict__ cost,
                                               float* __restrict__ out) {
  __shared__ float red[256];
  float part = 0.f;
  for (int b = threadIdx.x; b < NB; b += 256) {
    const float2 cb = cost[b];
    const float ce = fminf(cb.x, 1.0f);                       // exact cos (clip)
    const float cq = cb.y;                                    // fp8-replica cos
    const float s2 = fmaxf(fmaf(-cq, cq, 1.0f), 0.0f);
    const float sn = __builtin_amdgcn_sqrtf(s2);
    float tt = fmaf(cq, CA, CC);
    tt = fmaf(sn, -CB, tt);
    // k_main's add for the target column: fires if its m-group max > C0;
    // group-max >= cq, and when cq <= C0 the term underflows to 0 anyway.
    const float v_ctm = (cq > C0) ? __builtin_amdgcn_exp2f(tt) : 0.0f;
    const float logit_t = SCALE * (ce - MM);                  // true target logit
    const float v_tgt = __builtin_amdgcn_exp2f((logit_t - SCALE) * LOG2E);
    float sum = rowsum[b] - v_ctm + v_tgt;
    sum = fmaxf(sum, 1e-37f);
    part += __builtin_amdgcn_logf(sum) * 0.6931471805599453f + SCALE - logit_t;
  }
  red[threadIdx.x] = part;
  __syncthreads();
  #pragma unroll
  for (int s = 128; s > 0; s >>= 1) {
    if (threadIdx.x < s) red[threadIdx.x] += red[threadIdx.x + s];
    __syncthreads();
  }
  if (threadIdx.x == 0) out[0] = red[0] * (1.0f / NB);
}

extern "C" void kernel_launch(void* const* d_in, const int* in_sizes, int n_in,
                              void* d_out, int out_size, void* d_ws, size_t ws_size,
                              hipStream_t stream) {
  const float* x   = (const float*)d_in[0];
  const int*   tgt = (const int*)d_in[1];
  const float* w   = (const float*)d_in[2];
  float* out = (float*)d_out;

  char* ws = (char*)d_ws;
  const size_t WN_B = (size_t)NCP * 128;       // 13,107,200
  const size_t XN_B = (size_t)NB * 128;        // 262,144
  uint32_t* wn32   = (uint32_t*)ws;
  uint32_t* xn32   = (uint32_t*)(ws + WN_B);
  float2*   cost   = (float2*)(ws + WN_B + XN_B);
  float*    rowsum = (float*)(ws + WN_B + XN_B + NB * 8);
  if (ws_size < WN_B + XN_B + (size_t)NB * 12) return;

  k_norm_x<<<512,   256, 0, stream>>>(x, xn32, rowsum);
  k_norm_w<<<25600, 256, 0, stream>>>(w, wn32);
  k_tdot <<<512,   256, 0, stream>>>(x, w, xn32, wn32, tgt, cost);
  k_main <<<2048,  256, 0, stream>>>(xn32, wn32, rowsum);
  k_final<<<1,     256, 0, stream>>>(rowsum, cost, out);
}